// Round 1
// baseline (324.325 us; speedup 1.0000x reference)
//
#include <hip/hip_runtime.h>

// Problem constants (fixed by setup_inputs)
#define DD 160
#define HH 192
#define WW 160
constexpr int DHW = DD * HH * WW;

__global__ __launch_bounds__(256) void st_fused_kernel(
    const float* __restrict__ src,    // [1,1,D,H,W]
    const float* __restrict__ flow1,  // [1,3,D,H,W]
    const float* __restrict__ flow2,  // [1,3,D,H,W]
    const float* __restrict__ prf,    // scalar range_flow
    float* __restrict__ out)          // [DHW deform | 3*DHW out_flow]
{
    int idx = blockIdx.x * 256 + threadIdx.x;
    if (idx >= DHW) return;

    const float rf = prf[0];

    int x = idx % WW;
    int t = idx / WW;
    int y = t % HH;
    int z = t / HH;

    // flow2 channels at this voxel (channel 0=z/d, 1=y/h, 2=x/w)
    float f2z = flow2[idx];
    float f2y = flow2[idx + DHW];
    float f2x = flow2[idx + 2 * DHW];

    // ---- first grid_sample: sample flow1 at grid2 = grid + flow2*rf,
    // treated as NORMALIZED coords (this matches the reference exactly).
    float g2z = (float)z + f2z * rf;
    float g2y = (float)y + f2y * rf;
    float g2x = (float)x + f2x * rf;
    // align_corners=False unnorm: ((c+1)*S - 1) * 0.5
    float iz = ((g2z + 1.0f) * (float)DD - 1.0f) * 0.5f;
    float iy = ((g2y + 1.0f) * (float)HH - 1.0f) * 0.5f;
    float ix = ((g2x + 1.0f) * (float)WW - 1.0f) * 0.5f;

    float fwz = 0.0f, fwy = 0.0f, fwx = 0.0f;
    // Any in-bounds corner requires coord in (-1, S); otherwise all-zero.
    if (ix > -1.0f && ix < (float)WW &&
        iy > -1.0f && iy < (float)HH &&
        iz > -1.0f && iz < (float)DD) {
        float zf = floorf(iz), yf = floorf(iy), xf = floorf(ix);
        int z0 = (int)zf, y0 = (int)yf, x0 = (int)xf;
        float tz = iz - zf, ty = iy - yf, tx = ix - xf;
        #pragma unroll
        for (int dz = 0; dz < 2; ++dz) {
            int zc = z0 + dz;
            if (zc < 0 || zc >= DD) continue;
            float wz = dz ? tz : 1.0f - tz;
            #pragma unroll
            for (int dy = 0; dy < 2; ++dy) {
                int yc = y0 + dy;
                if (yc < 0 || yc >= HH) continue;
                float wzy = wz * (dy ? ty : 1.0f - ty);
                #pragma unroll
                for (int dx = 0; dx < 2; ++dx) {
                    int xc = x0 + dx;
                    if (xc < 0 || xc >= WW) continue;
                    float w = wzy * (dx ? tx : 1.0f - tx);
                    int off = (zc * HH + yc) * WW + xc;
                    fwz += w * flow1[off];
                    fwy += w * flow1[off + DHW];
                    fwx += w * flow1[off + 2 * DHW];
                }
            }
        }
    }

    // out_flow = flow1_warped + flow2
    float ofz = fwz + f2z;
    float ofy = fwy + f2y;
    float ofx = fwx + f2x;

    // ---- second grid_sample: src at normalized(grid + out_flow*rf)
    float nz = (float)z + ofz * rf;
    float ny = (float)y + ofy * rf;
    float nx = (float)x + ofx * rf;
    float cz = 2.0f * (nz / (float)(DD - 1) - 0.5f);
    float cy = 2.0f * (ny / (float)(HH - 1) - 0.5f);
    float cx = 2.0f * (nx / (float)(WW - 1) - 0.5f);
    float sz2 = ((cz + 1.0f) * (float)DD - 1.0f) * 0.5f;
    float sy2 = ((cy + 1.0f) * (float)HH - 1.0f) * 0.5f;
    float sx2 = ((cx + 1.0f) * (float)WW - 1.0f) * 0.5f;

    float sval = 0.0f;
    if (sx2 > -1.0f && sx2 < (float)WW &&
        sy2 > -1.0f && sy2 < (float)HH &&
        sz2 > -1.0f && sz2 < (float)DD) {
        float zf = floorf(sz2), yf = floorf(sy2), xf = floorf(sx2);
        int z0 = (int)zf, y0 = (int)yf, x0 = (int)xf;
        float tz = sz2 - zf, ty = sy2 - yf, tx = sx2 - xf;
        #pragma unroll
        for (int dz = 0; dz < 2; ++dz) {
            int zc = z0 + dz;
            if (zc < 0 || zc >= DD) continue;
            float wz = dz ? tz : 1.0f - tz;
            #pragma unroll
            for (int dy = 0; dy < 2; ++dy) {
                int yc = y0 + dy;
                if (yc < 0 || yc >= HH) continue;
                float wzy = wz * (dy ? ty : 1.0f - ty);
                #pragma unroll
                for (int dx = 0; dx < 2; ++dx) {
                    int xc = x0 + dx;
                    if (xc < 0 || xc >= WW) continue;
                    float w = wzy * (dx ? tx : 1.0f - tx);
                    sval += w * src[(zc * HH + yc) * WW + xc];
                }
            }
        }
    }

    // outputs: tuple (deform_2_img [DHW], out_flow [3*DHW]) concatenated
    out[idx] = sval;
    out[DHW + idx] = ofz;
    out[2 * DHW + idx] = ofy;
    out[3 * DHW + idx] = ofx;
}

extern "C" void kernel_launch(void* const* d_in, const int* in_sizes, int n_in,
                              void* d_out, int out_size, void* d_ws, size_t ws_size,
                              hipStream_t stream) {
    const float* src   = (const float*)d_in[0];
    const float* flow1 = (const float*)d_in[1];
    const float* flow2 = (const float*)d_in[2];
    // d_in[3] is the meshgrid `grid` — deterministic, computed analytically in-kernel.
    const float* prf   = (const float*)d_in[4];
    float* out = (float*)d_out;

    int blocks = (DHW + 255) / 256;
    st_fused_kernel<<<blocks, 256, 0, stream>>>(src, flow1, flow2, prf, out);
}

// Round 3
// 262.430 us; speedup vs baseline: 1.2359x; 1.2359x over previous
//
#include <hip/hip_runtime.h>

// Problem constants (fixed by setup_inputs)
#define DD 160
#define HH 192
#define WW 160
constexpr int DHW = DD * HH * WW;

typedef float vfloat4 __attribute__((ext_vector_type(4)));  // native vector for NT builtins

// Branchless trilinear sample of src (zeros padding) at (sz,sy,sx) voxel coords.
__device__ __forceinline__ float sample_src(const float* __restrict__ src,
                                            float sz, float sy, float sx) {
    float zf = floorf(sz), yf = floorf(sy), xf = floorf(sx);
    int z0 = (int)zf, y0 = (int)yf, x0 = (int)xf;
    float tz = sz - zf, ty = sy - yf, tx = sx - xf;

    float wz[2] = {1.0f - tz, tz};
    float wy[2] = {1.0f - ty, ty};
    float wx[2] = {1.0f - tx, tx};
    int zi[2], yi[2], xi[2];
    #pragma unroll
    for (int d = 0; d < 2; ++d) {
        int zc = z0 + d, yc = y0 + d, xc = x0 + d;
        if (zc < 0 || zc >= DD) wz[d] = 0.0f;
        if (yc < 0 || yc >= HH) wy[d] = 0.0f;
        if (xc < 0 || xc >= WW) wx[d] = 0.0f;
        zi[d] = min(max(zc, 0), DD - 1);
        yi[d] = min(max(yc, 0), HH - 1);
        xi[d] = min(max(xc, 0), WW - 1);
    }
    // Issue all 8 loads up front (independent), then combine.
    float v[8];
    #pragma unroll
    for (int dz = 0; dz < 2; ++dz)
        #pragma unroll
        for (int dy = 0; dy < 2; ++dy) {
            int rowoff = (zi[dz] * HH + yi[dy]) * WW;
            #pragma unroll
            for (int dx = 0; dx < 2; ++dx)
                v[dz * 4 + dy * 2 + dx] = src[rowoff + xi[dx]];
        }
    float acc = 0.0f;
    #pragma unroll
    for (int dz = 0; dz < 2; ++dz)
        #pragma unroll
        for (int dy = 0; dy < 2; ++dy)
            #pragma unroll
            for (int dx = 0; dx < 2; ++dx)
                acc += wz[dz] * wy[dy] * wx[dx] * v[dz * 4 + dy * 2 + dx];
    return acc;
}

__global__ __launch_bounds__(256) void st_fused_kernel(
    const float* __restrict__ src,    // [1,1,D,H,W]
    const float* __restrict__ flow1,  // [1,3,D,H,W]
    const float* __restrict__ flow2,  // [1,3,D,H,W]
    const float* __restrict__ prf,    // scalar range_flow
    float* __restrict__ out)          // [DHW deform | 3*DHW out_flow]
{
    int tid = blockIdx.x * 256 + threadIdx.x;
    int idx0 = tid * 4;                 // 4 consecutive x-voxels per thread
    if (idx0 >= DHW) return;            // DHW % 1024 == 0, so full groups only

    const float rf = prf[0];

    int xb = idx0 % WW;                 // group never crosses a row (WW%4==0)
    int t = idx0 / WW;
    int y = t % HH;
    int z = t / HH;

    const vfloat4 f2zv = *(const vfloat4*)(flow2 + idx0);
    const vfloat4 f2yv = *(const vfloat4*)(flow2 + idx0 + DHW);
    const vfloat4 f2xv = *(const vfloat4*)(flow2 + idx0 + 2 * DHW);

    vfloat4 sval, vofz, vofy, vofx;

    #pragma unroll
    for (int j = 0; j < 4; ++j) {
        int x = xb + j;
        float f2z = f2zv[j], f2y = f2yv[j], f2x = f2xv[j];

        // ---- first grid_sample: flow1 at grid2 = grid + flow2*rf treated as
        // NORMALIZED coords. Out of bounds for all but the (0,0,0) corner slab.
        float g2z = (float)z + f2z * rf;
        float g2y = (float)y + f2y * rf;
        float g2x = (float)x + f2x * rf;
        float iz = ((g2z + 1.0f) * (float)DD - 1.0f) * 0.5f;
        float iy = ((g2y + 1.0f) * (float)HH - 1.0f) * 0.5f;
        float ix = ((g2x + 1.0f) * (float)WW - 1.0f) * 0.5f;

        float fwz = 0.0f, fwy = 0.0f, fwx = 0.0f;
        if (ix > -1.0f && ix < (float)WW &&
            iy > -1.0f && iy < (float)HH &&
            iz > -1.0f && iz < (float)DD) {        // rare, wave-uniform skip
            float zf = floorf(iz), yf = floorf(iy), xf = floorf(ix);
            int z0 = (int)zf, y0 = (int)yf, x0 = (int)xf;
            float tz = iz - zf, ty = iy - yf, tx = ix - xf;
            #pragma unroll
            for (int dz = 0; dz < 2; ++dz) {
                int zc = z0 + dz;
                if (zc < 0 || zc >= DD) continue;
                float wz = dz ? tz : 1.0f - tz;
                #pragma unroll
                for (int dy = 0; dy < 2; ++dy) {
                    int yc = y0 + dy;
                    if (yc < 0 || yc >= HH) continue;
                    float wzy = wz * (dy ? ty : 1.0f - ty);
                    #pragma unroll
                    for (int dx = 0; dx < 2; ++dx) {
                        int xc = x0 + dx;
                        if (xc < 0 || xc >= WW) continue;
                        float w = wzy * (dx ? tx : 1.0f - tx);
                        int off = (zc * HH + yc) * WW + xc;
                        fwz += w * flow1[off];
                        fwy += w * flow1[off + DHW];
                        fwx += w * flow1[off + 2 * DHW];
                    }
                }
            }
        }

        // out_flow = flow1_warped + flow2
        float ofz = fwz + f2z;
        float ofy = fwy + f2y;
        float ofx = fwx + f2x;
        vofz[j] = ofz; vofy[j] = ofy; vofx[j] = ofx;

        // ---- second grid_sample: src at normalized(grid + out_flow*rf)
        float nz = (float)z + ofz * rf;
        float ny = (float)y + ofy * rf;
        float nx = (float)x + ofx * rf;
        float cz = 2.0f * (nz / (float)(DD - 1) - 0.5f);
        float cy = 2.0f * (ny / (float)(HH - 1) - 0.5f);
        float cx = 2.0f * (nx / (float)(WW - 1) - 0.5f);
        float sz2 = ((cz + 1.0f) * (float)DD - 1.0f) * 0.5f;
        float sy2 = ((cy + 1.0f) * (float)HH - 1.0f) * 0.5f;
        float sx2 = ((cx + 1.0f) * (float)WW - 1.0f) * 0.5f;

        sval[j] = sample_src(src, sz2, sy2, sx2);
    }

    // outputs: (deform [DHW], out_flow [3*DHW]) concatenated; NT stores —
    // never re-read, keep them out of L2 so the src gather set stays hot.
    __builtin_nontemporal_store(sval, (vfloat4*)(out + idx0));
    __builtin_nontemporal_store(vofz, (vfloat4*)(out + DHW + idx0));
    __builtin_nontemporal_store(vofy, (vfloat4*)(out + 2 * DHW + idx0));
    __builtin_nontemporal_store(vofx, (vfloat4*)(out + 3 * DHW + idx0));
}

extern "C" void kernel_launch(void* const* d_in, const int* in_sizes, int n_in,
                              void* d_out, int out_size, void* d_ws, size_t ws_size,
                              hipStream_t stream) {
    const float* src   = (const float*)d_in[0];
    const float* flow1 = (const float*)d_in[1];
    const float* flow2 = (const float*)d_in[2];
    // d_in[3] is the meshgrid `grid` — deterministic, computed analytically in-kernel.
    const float* prf   = (const float*)d_in[4];
    float* out = (float*)d_out;

    int threads_total = DHW / 4;
    int blocks = (threads_total + 255) / 256;
    st_fused_kernel<<<blocks, 256, 0, stream>>>(src, flow1, flow2, prf, out);
}